// Round 6
// baseline (149.975 us; speedup 1.0000x reference)
//
#include <hip/hip_runtime.h>
#include <hip/hip_bf16.h>

typedef __bf16 bf16;
typedef __attribute__((ext_vector_type(8))) __bf16 bf16x8;
typedef __attribute__((ext_vector_type(4))) float f32x4;
typedef __attribute__((ext_vector_type(4))) int i32x4;
typedef __attribute__((ext_vector_type(2))) int i32x2;

#define CH 192
#define MAT (CH * CH)            // 36864
#define NF 145                   // canonical frequencies of 17x17 grid (conj symmetry)
#define FSTRIDE (2 * MAT)        // Re+Im per freq
#define NELEM (CH * CH * 9)      // 331776
#define XSCALE 9.765625e-4f      // 2^-10, exact; sigma = 1024*(s3/289)^(1/16)
#define W17 0.36959913571644626f // 2*pi/17
#define NGRAM (8 * 19 * 3)       // 456 gram blocks (435 active)
#define NACT 435                 // active gram blocks (f < NF)
#define NSCALE 324               // spinner blocks fused into gram-C

// ---------------------------------------------------------------------------
// sigma = ||G^3(K)||_F^(1/8) via 17x17 spectral sampling (exact Parseval).
// k_dftm: the 145-freq DFT is a GEMM X[36864x290] = K[36864x9] x T[9x290],
//   done in bf16 MFMA with hi/lo split of BOTH operands (3 passes) => X is
//   fp32-path-accurate after its bf16 store. Was 4.2 us VALU-bound; now <1 us.
// Gram rounds: Hermitian 3-quadrant compute (q=0,1,2), (96,0) = conj-T of
//   (0,96) via pre-transposed LDS tile. Staging FULLY UNROLLED (round-4
//   spill lesson: runtime trip counts scratch v[] — do not regress).
// Gram-C carries 324 extra spinner blocks that wait on cnt==435 then do the
//   K/sigma scale (deadlock-safe: 324 < 512-block residency).
// ws layout: [0] float s3; [4] int cnt; [256] bufX bf16 [f][2][a][o]; bufH.
// ---------------------------------------------------------------------------

// X[f][part][a*192+o] = DFT(K[o][a])(w_f) * 2^-10 via MFMA.
// Grid 288 x 256: block = 128 p-rows, all 304 cols (c = 2f+part, pad >=290).
#define TSTR 40                  // T row stride (bf16): 20 dwords -> 2/bank, free
__global__ __launch_bounds__(256) void k_dftm(const float* __restrict__ K,
                                              bf16* __restrict__ X,
                                              float* __restrict__ s3,
                                              int* __restrict__ cnt) {
    __shared__ bf16 Th[304 * TSTR], Tl[304 * TSTR];
    __shared__ float twc[17], tws[17];
    int tid = threadIdx.x;
    if (blockIdx.x == 0 && tid == 0) { *s3 = 0.0f; *cnt = 0; }
    if (tid < 17) {
        float s, c;
        __sincosf(-W17 * (float)tid, &s, &c);
        twc[tid] = c; tws[tid] = s;
    }
    // zero T (b64 chunks), then fill live entries (c<290, k<9)
    for (int i = tid; i < 304 * TSTR / 4; i += 256) {
        ((i32x2*)Th)[i] = i32x2{0, 0};
        ((i32x2*)Tl)[i] = i32x2{0, 0};
    }
    __syncthreads();               // twc/tws ready (and zeros done)
    for (int pr = tid; pr < NF * 9; pr += 256) {   // 1305 pairs (f,k)
        int f = pr / 9, k = pr % 9;
        int fy, fx;
        if (f < 9) { fy = 0; fx = f; }
        else { int u = f - 9; fy = 1 + u / 17; fx = u % 17; }
        int ph = (fy * (k / 3) + fx * (k % 3)) % 17;
        float vr = twc[ph] * XSCALE, vi = tws[ph] * XSCALE;
        bf16 hr = (bf16)vr, hi = (bf16)vi;
        Th[(2 * f) * TSTR + k] = hr;  Tl[(2 * f) * TSTR + k] = (bf16)(vr - (float)hr);
        Th[(2 * f + 1) * TSTR + k] = hi;  Tl[(2 * f + 1) * TSTR + k] = (bf16)(vi - (float)hi);
    }
    __syncthreads();

    int lane = tid & 63, w = tid >> 6;
    int ml = lane & 15, kq4 = lane >> 4;
    int Pb0 = blockIdx.x * 128;
    bf16x8 Ah[2], Al[2];
#pragma unroll
    for (int pt = 0; pt < 2; ++pt) {
        int p = Pb0 + (w * 2 + pt) * 16 + ml;
        int a = p / CH, o = p % CH;
        const float* src = K + (size_t)(o * CH + a) * 9;
        bf16x8 h8, l8;
#pragma unroll
        for (int jj = 0; jj < 8; ++jj) {
            int k = kq4 * 8 + jj;
            float kv = (k < 9) ? src[k] : 0.0f;
            bf16 h = (bf16)kv;
            h8[jj] = h;
            l8[jj] = (bf16)(kv - (float)h);
        }
        Ah[pt] = h8; Al[pt] = l8;
    }
#pragma unroll 4
    for (int ct = 0; ct < 19; ++ct) {
        int c = ct * 16 + ml;
        bf16x8 Bh = *(const bf16x8*)&Th[c * TSTR + kq4 * 8];
        bf16x8 Bl = *(const bf16x8*)&Tl[c * TSTR + kq4 * 8];
#pragma unroll
        for (int pt = 0; pt < 2; ++pt) {
            f32x4 acc = f32x4{0.f, 0.f, 0.f, 0.f};
            acc = __builtin_amdgcn_mfma_f32_16x16x32_bf16(Al[pt], Bh, acc, 0, 0, 0);
            acc = __builtin_amdgcn_mfma_f32_16x16x32_bf16(Ah[pt], Bl, acc, 0, 0, 0);
            acc = __builtin_amdgcn_mfma_f32_16x16x32_bf16(Ah[pt], Bh, acc, 0, 0, 0);
            if (c < 2 * NF) {                       // f <= 144
                int f = c >> 1, part = c & 1;
                int p0 = Pb0 + (w * 2 + pt) * 16 + kq4 * 4;
                bf16* dst = X + (size_t)f * FSTRIDE + part * MAT + p0;
                alignas(8) bf16 tmp[4];
#pragma unroll
                for (int r = 0; r < 4; ++r) tmp[r] = (bf16)acc[r];
                *(i32x2*)dst = *(const i32x2*)tmp;
            }
        }
    }
}

// One conj-gram round: OUT[m,n] = sum_k conj(X[m,k]) * X[n,k]  (per freq).
// Quadrants q=0:(0,0) q=1:(0,96) q=2:(96,96); WRITE emits (96,0)=conj-T(q=1).
// NORM weights q=1 by 2 and carries NSCALE spinner blocks for the scale.
#define LDSR 72                  // 64 + 8 bf16 pad (row stride 36 dwords)
#define SLAB (96 * LDSR)         // 6912 elems
#define OLDSR 104                // epilogue tile stride: 208 B = 13*16 (b128 rows)

template <bool WRITE, bool NORM>
__global__ __launch_bounds__(256, 2) void k_gram(const bf16* __restrict__ X,
                                                 bf16* __restrict__ Y,
                                                 float* __restrict__ s3,
                                                 int* __restrict__ cnt,
                                                 const float* __restrict__ Kin,
                                                 float* __restrict__ outp) {
    __shared__ bf16 lds[4 * SLAB];      // Ar Ai Br Bi : 55296 B (epilogue reuses)
    __shared__ float red[4];
    int bid = blockIdx.x;
    int tid = threadIdx.x;

    if (NORM && bid >= NGRAM) {
        // spinner block: wait for all 435 gram blocks, then out = K / sigma
        int sb = bid - NGRAM;
        if (tid == 0) {
            while (__hip_atomic_load(cnt, __ATOMIC_ACQUIRE, __HIP_MEMORY_SCOPE_AGENT) < NACT)
                __builtin_amdgcn_s_sleep(32);
        }
        __syncthreads();
        float sv = __hip_atomic_load(s3, __ATOMIC_RELAXED, __HIP_MEMORY_SCOPE_AGENT);
        float sig = 1024.0f * exp2f(log2f(sv * (1.0f / 289.0f)) * 0.0625f);
        float inv = 1.0f / sig;
        int i = (sb * 256 + tid) * 4;   // 324*1024 = NELEM exact
        f32x4 v = *(const f32x4*)(Kin + i);
        v *= inv;
        *(f32x4*)(outp + i) = v;
        return;
    }

    int xcd = bid & 7, r = bid >> 3;
    int fi = r / 3, q = r % 3;          // q: 0=(0,0) 1=(0,96) 2=(96,96)
    int f = xcd + 8 * fi;
    if (f >= NF) return;                // uniform; before any barrier
    int row0 = (q == 2) ? 96 : 0;
    int col0 = (q >= 1) ? 96 : 0;
    bool diag = (q != 1);
    int sb2 = diag ? 0 : 2;             // B-slab base (diag reuses A slabs)
    const bf16* Xf = X + (size_t)f * FSTRIDE;

    int lane = tid & 63, w = tid >> 6;
    int wr = (w >> 1) * 48, wc = (w & 1) * 48;
    int ml = lane & 15, kq = (lane >> 4) * 8;

    f32x4 cr[3][3], ci[3][3];
#pragma unroll
    for (int i = 0; i < 3; ++i)
#pragma unroll
        for (int j = 0; j < 3; ++j) {
            cr[i][j] = f32x4{0.f, 0.f, 0.f, 0.f};
            ci[i][j] = f32x4{0.f, 0.f, 0.f, 0.f};
        }

    for (int kc = 0; kc < CH; kc += 64) {
        // FULLY UNROLLED staging (compile-time v[] indices — no scratch!)
        i32x4 v[12];
#pragma unroll
        for (int s = 0; s < 2; ++s) {               // A slabs (always)
            const bf16* src = Xf + (s ? MAT : 0) + (size_t)row0 * CH + kc;
#pragma unroll
            for (int j = 0; j < 3; ++j) {
                int chunk = j * 256 + tid;
                int rr = chunk >> 3, c8 = chunk & 7;
                v[s * 3 + j] = *(const i32x4*)(src + rr * CH + c8 * 8);
            }
        }
        if (!diag) {
#pragma unroll
            for (int s = 2; s < 4; ++s) {           // B slabs (off-diag only)
                const bf16* src = Xf + ((s & 1) ? MAT : 0) + (size_t)col0 * CH + kc;
#pragma unroll
                for (int j = 0; j < 3; ++j) {
                    int chunk = j * 256 + tid;
                    int rr = chunk >> 3, c8 = chunk & 7;
                    v[s * 3 + j] = *(const i32x4*)(src + rr * CH + c8 * 8);
                }
            }
        }
        __syncthreads();
#pragma unroll
        for (int s = 0; s < 2; ++s)
#pragma unroll
            for (int j = 0; j < 3; ++j) {
                int chunk = j * 256 + tid;
                int rr = chunk >> 3, c8 = chunk & 7;
                *(i32x4*)&lds[s * SLAB + rr * LDSR + c8 * 8] = v[s * 3 + j];
            }
        if (!diag) {
#pragma unroll
            for (int s = 2; s < 4; ++s)
#pragma unroll
                for (int j = 0; j < 3; ++j) {
                    int chunk = j * 256 + tid;
                    int rr = chunk >> 3, c8 = chunk & 7;
                    *(i32x4*)&lds[s * SLAB + rr * LDSR + c8 * 8] = v[s * 3 + j];
                }
        }
        __syncthreads();

#pragma unroll
        for (int ks = 0; ks < 64; ks += 32) {
            bf16x8 ar[3], ai[3], nai[3], br[3], bi[3];
            int ko = ks + kq;
#pragma unroll
            for (int mt = 0; mt < 3; ++mt) {
                ar[mt] = *(const bf16x8*)&lds[0 * SLAB + (wr + mt * 16 + ml) * LDSR + ko];
                ai[mt] = *(const bf16x8*)&lds[1 * SLAB + (wr + mt * 16 + ml) * LDSR + ko];
                br[mt] = *(const bf16x8*)&lds[(sb2 + 0) * SLAB + (wc + mt * 16 + ml) * LDSR + ko];
                bi[mt] = *(const bf16x8*)&lds[(sb2 + 1) * SLAB + (wc + mt * 16 + ml) * LDSR + ko];
                i32x4 u = __builtin_bit_cast(i32x4, ai[mt]);
                u ^= 0x80008000;   // negate 8 bf16
                nai[mt] = __builtin_bit_cast(bf16x8, u);
            }
#pragma unroll
            for (int mt = 0; mt < 3; ++mt)
#pragma unroll
                for (int nt = 0; nt < 3; ++nt) {
                    cr[mt][nt] = __builtin_amdgcn_mfma_f32_16x16x32_bf16(ar[mt],  br[nt], cr[mt][nt], 0, 0, 0);
                    cr[mt][nt] = __builtin_amdgcn_mfma_f32_16x16x32_bf16(ai[mt],  bi[nt], cr[mt][nt], 0, 0, 0);
                    ci[mt][nt] = __builtin_amdgcn_mfma_f32_16x16x32_bf16(ar[mt],  bi[nt], ci[mt][nt], 0, 0, 0);
                    ci[mt][nt] = __builtin_amdgcn_mfma_f32_16x16x32_bf16(nai[mt], br[nt], ci[mt][nt], 0, 0, 0);
                }
        }
    }

    if (WRITE) {
        // frag -> LDS tile(s) -> coalesced b128 row stores; q=1 scatters conj
        // into a pre-transposed second tile for the (96,0) quadrant.
        bf16* tileA = lds;
        bf16* tileB = lds + 96 * OLDSR;     // 19968 B each, 39936 <= 55296
        bf16* Yf = Y + (size_t)f * FSTRIDE;
        int lr0 = wr + (lane >> 4) * 4;
        int lc0 = wc + ml;
#pragma unroll
        for (int part = 0; part < 2; ++part) {
            __syncthreads();   // frag LDS reads / prev part's global reads done
#pragma unroll
            for (int mt = 0; mt < 3; ++mt)
#pragma unroll
                for (int nt = 0; nt < 3; ++nt)
#pragma unroll
                    for (int rr = 0; rr < 4; ++rr) {
                        float vv = part ? ci[mt][nt][rr] : cr[mt][nt][rr];
                        int rrow = lr0 + mt * 16 + rr;
                        int ccol = lc0 + nt * 16;
                        tileA[rrow * OLDSR + ccol] = (bf16)vv;
                        if (q == 1)
                            tileB[ccol * OLDSR + rrow] = (bf16)(part ? -vv : vv);
                    }
            __syncthreads();
            bf16* dst = Yf + (part ? MAT : 0) + (size_t)row0 * CH + col0;
            for (int ch = tid; ch < 96 * 12; ch += 256) {
                int rw = ch / 12, cc = ch % 12;
                *(i32x4*)&dst[(size_t)rw * CH + cc * 8] = *(const i32x4*)&tileA[rw * OLDSR + cc * 8];
            }
            if (q == 1) {
                bf16* dst2 = Yf + (part ? MAT : 0) + (size_t)col0 * CH + row0;
                for (int ch = tid; ch < 96 * 12; ch += 256) {
                    int rw = ch / 12, cc = ch % 12;
                    *(i32x4*)&dst2[(size_t)rw * CH + cc * 8] = *(const i32x4*)&tileB[rw * OLDSR + cc * 8];
                }
            }
        }
    }
    if (NORM) {
        float loc = 0.f;
#pragma unroll
        for (int mt = 0; mt < 3; ++mt)
#pragma unroll
            for (int nt = 0; nt < 3; ++nt)
#pragma unroll
                for (int rr = 0; rr < 4; ++rr)
                    loc += cr[mt][nt][rr] * cr[mt][nt][rr] + ci[mt][nt][rr] * ci[mt][nt][rr];
#pragma unroll
        for (int off = 32; off > 0; off >>= 1) loc += __shfl_down(loc, off, 64);
        if (lane == 0) red[w] = loc;
        __syncthreads();
        if (tid == 0) {
            float base = (f == 0) ? 1.0f : 2.0f;    // conj-pair weight over freqs
            float wq = (q == 1) ? 2.0f : 1.0f;      // Hermitian quadrant weight
            atomicAdd(s3, base * wq * (red[0] + red[1] + red[2] + red[3]));
            __threadfence();                        // release s3 before count
            atomicAdd(cnt, 1);
        }
    }
}

extern "C" void kernel_launch(void* const* d_in, const int* in_sizes, int n_in,
                              void* d_out, int out_size, void* d_ws, size_t ws_size,
                              hipStream_t stream) {
    const float* K = (const float*)d_in[0];
    float* out = (float*)d_out;
    char* ws = (char*)d_ws;
    float* s3 = (float*)ws;
    int* cnt = (int*)(ws + 4);
    bf16* bufX = (bf16*)(ws + 256);
    bf16* bufH = bufX + (size_t)NF * FSTRIDE;

    k_dftm<<<288, 256, 0, stream>>>(K, bufX, s3, cnt);                            // X
    k_gram<true,  false><<<NGRAM, 256, 0, stream>>>(bufX, bufH, nullptr, nullptr, nullptr, nullptr);  // H1
    k_gram<true,  false><<<NGRAM, 256, 0, stream>>>(bufH, bufX, nullptr, nullptr, nullptr, nullptr);  // H2
    k_gram<false, true ><<<NGRAM + NSCALE, 256, 0, stream>>>(bufX, nullptr, s3, cnt, K, out);         // ||H3||^2 + scale
}

// Round 7
// 112.413 us; speedup vs baseline: 1.3341x; 1.3341x over previous
//
#include <hip/hip_runtime.h>
#include <hip/hip_bf16.h>

typedef __bf16 bf16;
typedef __attribute__((ext_vector_type(8))) __bf16 bf16x8;
typedef __attribute__((ext_vector_type(4))) float f32x4;
typedef __attribute__((ext_vector_type(4))) int i32x4;
typedef __attribute__((ext_vector_type(2))) int i32x2;

#define CH 192
#define MAT (CH * CH)            // 36864
#define NF 145                   // canonical frequencies of 17x17 grid (conj symmetry)
#define FSTRIDE (2 * MAT)        // Re+Im per freq
#define NELEM (CH * CH * 9)      // 331776
#define XSCALE 9.765625e-4f      // 2^-10, exact; sigma = 1024*(s3/289)^(1/16)
#define W17 0.36959913571644626f // 2*pi/17
#define NGRAM (8 * 19 * 3)       // 456 gram blocks (435 active)

// ---------------------------------------------------------------------------
// sigma = ||G^3(K)||_F^(1/8) via 17x17 spectral sampling (exact Parseval).
// k_dftm: 145-freq DFT as GEMM X[36864x290] = K[36864x9] x T[9x290] in bf16
//   MFMA with hi/lo split of BOTH operands (3 passes) — fp32-path-accurate
//   after the bf16 store (verified round 6: absmax identical).
// Gram rounds: Hermitian 3-quadrant compute (q=0,1,2), (96,0) = conj-T of
//   (0,96) via pre-transposed LDS tile. Staging FULLY UNROLLED (round-4
//   lesson: runtime trip counts spill v[] to scratch — do not regress).
// Round-6 lesson: spinner-block fusion of the scale (agent-scope polling)
//   cost +40 us (L2-invalidate storm evicting pinned data). Keep k_scale as
//   its own dispatch — do not re-fuse with spin-waits.
// XCD pinning: freq f handled by blocks with blockIdx%8 == f%8.
// ws layout: [0] float s3; [256] bufX bf16 [f][2][a][o]; bufH (~21.4 MB ea).
// ---------------------------------------------------------------------------

// X[f][part][a*192+o] = DFT(K[o][a])(w_f) * 2^-10 via MFMA.
// Grid 288 x 256: block = 128 p-rows, all 304 cols (c = 2f+part, pad >=290).
#define TSTR 40                  // T row stride (bf16): 20 dwords -> 2/bank, free
__global__ __launch_bounds__(256) void k_dftm(const float* __restrict__ K,
                                              bf16* __restrict__ X,
                                              float* __restrict__ s3) {
    __shared__ bf16 Th[304 * TSTR], Tl[304 * TSTR];
    __shared__ float twc[17], tws[17];
    int tid = threadIdx.x;
    if (blockIdx.x == 0 && tid == 0) *s3 = 0.0f;   // stream-ordered vs gram-C
    if (tid < 17) {
        float s, c;
        __sincosf(-W17 * (float)tid, &s, &c);
        twc[tid] = c; tws[tid] = s;
    }
    // zero T (b64 chunks), then fill live entries (c<290, k<9)
    for (int i = tid; i < 304 * TSTR / 4; i += 256) {
        ((i32x2*)Th)[i] = i32x2{0, 0};
        ((i32x2*)Tl)[i] = i32x2{0, 0};
    }
    __syncthreads();               // twc/tws ready (and zeros done)
    for (int pr = tid; pr < NF * 9; pr += 256) {   // 1305 pairs (f,k)
        int f = pr / 9, k = pr % 9;
        int fy, fx;
        if (f < 9) { fy = 0; fx = f; }
        else { int u = f - 9; fy = 1 + u / 17; fx = u % 17; }
        int ph = (fy * (k / 3) + fx * (k % 3)) % 17;
        float vr = twc[ph] * XSCALE, vi = tws[ph] * XSCALE;
        bf16 hr = (bf16)vr, hi = (bf16)vi;
        Th[(2 * f) * TSTR + k] = hr;  Tl[(2 * f) * TSTR + k] = (bf16)(vr - (float)hr);
        Th[(2 * f + 1) * TSTR + k] = hi;  Tl[(2 * f + 1) * TSTR + k] = (bf16)(vi - (float)hi);
    }
    __syncthreads();

    int lane = tid & 63, w = tid >> 6;
    int ml = lane & 15, kq4 = lane >> 4;
    int Pb0 = blockIdx.x * 128;
    bf16x8 Ah[2], Al[2];
#pragma unroll
    for (int pt = 0; pt < 2; ++pt) {
        int p = Pb0 + (w * 2 + pt) * 16 + ml;
        int a = p / CH, o = p % CH;
        const float* src = K + (size_t)(o * CH + a) * 9;
        bf16x8 h8, l8;
#pragma unroll
        for (int jj = 0; jj < 8; ++jj) {
            int k = kq4 * 8 + jj;
            float kv = (k < 9) ? src[k] : 0.0f;
            bf16 h = (bf16)kv;
            h8[jj] = h;
            l8[jj] = (bf16)(kv - (float)h);
        }
        Ah[pt] = h8; Al[pt] = l8;
    }
#pragma unroll 4
    for (int ct = 0; ct < 19; ++ct) {
        int c = ct * 16 + ml;
        bf16x8 Bh = *(const bf16x8*)&Th[c * TSTR + kq4 * 8];
        bf16x8 Bl = *(const bf16x8*)&Tl[c * TSTR + kq4 * 8];
#pragma unroll
        for (int pt = 0; pt < 2; ++pt) {
            f32x4 acc = f32x4{0.f, 0.f, 0.f, 0.f};
            acc = __builtin_amdgcn_mfma_f32_16x16x32_bf16(Al[pt], Bh, acc, 0, 0, 0);
            acc = __builtin_amdgcn_mfma_f32_16x16x32_bf16(Ah[pt], Bl, acc, 0, 0, 0);
            acc = __builtin_amdgcn_mfma_f32_16x16x32_bf16(Ah[pt], Bh, acc, 0, 0, 0);
            if (c < 2 * NF) {                       // f <= 144
                int f = c >> 1, part = c & 1;
                int p0 = Pb0 + (w * 2 + pt) * 16 + kq4 * 4;
                bf16* dst = X + (size_t)f * FSTRIDE + part * MAT + p0;
                alignas(8) bf16 tmp[4];
#pragma unroll
                for (int r = 0; r < 4; ++r) tmp[r] = (bf16)acc[r];
                *(i32x2*)dst = *(const i32x2*)tmp;
            }
        }
    }
}

// One conj-gram round: OUT[m,n] = sum_k conj(X[m,k]) * X[n,k]  (per freq).
// Quadrants q=0:(0,0) q=1:(0,96) q=2:(96,96); WRITE emits (96,0)=conj-T(q=1).
// NORM weights q=1 by 2. Block 256 = 4 waves, wave = 48x48 complex.
#define LDSR 72                  // 64 + 8 bf16 pad (row stride 36 dwords)
#define SLAB (96 * LDSR)         // 6912 elems
#define OLDSR 104                // epilogue tile stride: 208 B = 13*16 (b128 rows)

template <bool WRITE, bool NORM>
__global__ __launch_bounds__(256, 2) void k_gram(const bf16* __restrict__ X,
                                                 bf16* __restrict__ Y,
                                                 float* __restrict__ s3) {
    __shared__ bf16 lds[4 * SLAB];      // Ar Ai Br Bi : 55296 B (epilogue reuses)
    __shared__ float red[4];
    int bid = blockIdx.x;
    int xcd = bid & 7, r = bid >> 3;
    int fi = r / 3, q = r % 3;          // q: 0=(0,0) 1=(0,96) 2=(96,96)
    int f = xcd + 8 * fi;
    if (f >= NF) return;                // uniform; before any barrier
    int row0 = (q == 2) ? 96 : 0;
    int col0 = (q >= 1) ? 96 : 0;
    bool diag = (q != 1);
    int sb2 = diag ? 0 : 2;             // B-slab base (diag reuses A slabs)
    const bf16* Xf = X + (size_t)f * FSTRIDE;

    int tid = threadIdx.x;
    int lane = tid & 63, w = tid >> 6;
    int wr = (w >> 1) * 48, wc = (w & 1) * 48;
    int ml = lane & 15, kq = (lane >> 4) * 8;

    f32x4 cr[3][3], ci[3][3];
#pragma unroll
    for (int i = 0; i < 3; ++i)
#pragma unroll
        for (int j = 0; j < 3; ++j) {
            cr[i][j] = f32x4{0.f, 0.f, 0.f, 0.f};
            ci[i][j] = f32x4{0.f, 0.f, 0.f, 0.f};
        }

    for (int kc = 0; kc < CH; kc += 64) {
        // FULLY UNROLLED staging (compile-time v[] indices — no scratch!)
        i32x4 v[12];
#pragma unroll
        for (int s = 0; s < 2; ++s) {               // A slabs (always)
            const bf16* src = Xf + (s ? MAT : 0) + (size_t)row0 * CH + kc;
#pragma unroll
            for (int j = 0; j < 3; ++j) {
                int chunk = j * 256 + tid;
                int rr = chunk >> 3, c8 = chunk & 7;
                v[s * 3 + j] = *(const i32x4*)(src + rr * CH + c8 * 8);
            }
        }
        if (!diag) {
#pragma unroll
            for (int s = 2; s < 4; ++s) {           // B slabs (off-diag only)
                const bf16* src = Xf + ((s & 1) ? MAT : 0) + (size_t)col0 * CH + kc;
#pragma unroll
                for (int j = 0; j < 3; ++j) {
                    int chunk = j * 256 + tid;
                    int rr = chunk >> 3, c8 = chunk & 7;
                    v[s * 3 + j] = *(const i32x4*)(src + rr * CH + c8 * 8);
                }
            }
        }
        __syncthreads();
#pragma unroll
        for (int s = 0; s < 2; ++s)
#pragma unroll
            for (int j = 0; j < 3; ++j) {
                int chunk = j * 256 + tid;
                int rr = chunk >> 3, c8 = chunk & 7;
                *(i32x4*)&lds[s * SLAB + rr * LDSR + c8 * 8] = v[s * 3 + j];
            }
        if (!diag) {
#pragma unroll
            for (int s = 2; s < 4; ++s)
#pragma unroll
                for (int j = 0; j < 3; ++j) {
                    int chunk = j * 256 + tid;
                    int rr = chunk >> 3, c8 = chunk & 7;
                    *(i32x4*)&lds[s * SLAB + rr * LDSR + c8 * 8] = v[s * 3 + j];
                }
        }
        __syncthreads();

#pragma unroll
        for (int ks = 0; ks < 64; ks += 32) {
            bf16x8 ar[3], ai[3], nai[3], br[3], bi[3];
            int ko = ks + kq;
#pragma unroll
            for (int mt = 0; mt < 3; ++mt) {
                ar[mt] = *(const bf16x8*)&lds[0 * SLAB + (wr + mt * 16 + ml) * LDSR + ko];
                ai[mt] = *(const bf16x8*)&lds[1 * SLAB + (wr + mt * 16 + ml) * LDSR + ko];
                br[mt] = *(const bf16x8*)&lds[(sb2 + 0) * SLAB + (wc + mt * 16 + ml) * LDSR + ko];
                bi[mt] = *(const bf16x8*)&lds[(sb2 + 1) * SLAB + (wc + mt * 16 + ml) * LDSR + ko];
                i32x4 u = __builtin_bit_cast(i32x4, ai[mt]);
                u ^= 0x80008000;   // negate 8 bf16
                nai[mt] = __builtin_bit_cast(bf16x8, u);
            }
#pragma unroll
            for (int mt = 0; mt < 3; ++mt)
#pragma unroll
                for (int nt = 0; nt < 3; ++nt) {
                    cr[mt][nt] = __builtin_amdgcn_mfma_f32_16x16x32_bf16(ar[mt],  br[nt], cr[mt][nt], 0, 0, 0);
                    cr[mt][nt] = __builtin_amdgcn_mfma_f32_16x16x32_bf16(ai[mt],  bi[nt], cr[mt][nt], 0, 0, 0);
                    ci[mt][nt] = __builtin_amdgcn_mfma_f32_16x16x32_bf16(ar[mt],  bi[nt], ci[mt][nt], 0, 0, 0);
                    ci[mt][nt] = __builtin_amdgcn_mfma_f32_16x16x32_bf16(nai[mt], br[nt], ci[mt][nt], 0, 0, 0);
                }
        }
    }

    if (WRITE) {
        // frag -> LDS tile(s) -> coalesced b128 row stores; q=1 scatters conj
        // into a pre-transposed second tile for the (96,0) quadrant.
        bf16* tileA = lds;
        bf16* tileB = lds + 96 * OLDSR;     // 19968 B each, 39936 <= 55296
        bf16* Yf = Y + (size_t)f * FSTRIDE;
        int lr0 = wr + (lane >> 4) * 4;
        int lc0 = wc + ml;
#pragma unroll
        for (int part = 0; part < 2; ++part) {
            __syncthreads();   // frag LDS reads / prev part's global reads done
#pragma unroll
            for (int mt = 0; mt < 3; ++mt)
#pragma unroll
                for (int nt = 0; nt < 3; ++nt)
#pragma unroll
                    for (int rr = 0; rr < 4; ++rr) {
                        float vv = part ? ci[mt][nt][rr] : cr[mt][nt][rr];
                        int rrow = lr0 + mt * 16 + rr;
                        int ccol = lc0 + nt * 16;
                        tileA[rrow * OLDSR + ccol] = (bf16)vv;
                        if (q == 1)
                            tileB[ccol * OLDSR + rrow] = (bf16)(part ? -vv : vv);
                    }
            __syncthreads();
            bf16* dst = Yf + (part ? MAT : 0) + (size_t)row0 * CH + col0;
            for (int ch = tid; ch < 96 * 12; ch += 256) {
                int rw = ch / 12, cc = ch % 12;
                *(i32x4*)&dst[(size_t)rw * CH + cc * 8] = *(const i32x4*)&tileA[rw * OLDSR + cc * 8];
            }
            if (q == 1) {
                bf16* dst2 = Yf + (part ? MAT : 0) + (size_t)col0 * CH + row0;
                for (int ch = tid; ch < 96 * 12; ch += 256) {
                    int rw = ch / 12, cc = ch % 12;
                    *(i32x4*)&dst2[(size_t)rw * CH + cc * 8] = *(const i32x4*)&tileB[rw * OLDSR + cc * 8];
                }
            }
        }
    }
    if (NORM) {
        float loc = 0.f;
#pragma unroll
        for (int mt = 0; mt < 3; ++mt)
#pragma unroll
            for (int nt = 0; nt < 3; ++nt)
#pragma unroll
                for (int rr = 0; rr < 4; ++rr)
                    loc += cr[mt][nt][rr] * cr[mt][nt][rr] + ci[mt][nt][rr] * ci[mt][nt][rr];
#pragma unroll
        for (int off = 32; off > 0; off >>= 1) loc += __shfl_down(loc, off, 64);
        if (lane == 0) red[w] = loc;
        __syncthreads();
        if (tid == 0) {
            float base = (f == 0) ? 1.0f : 2.0f;    // conj-pair weight over freqs
            float wq = (q == 1) ? 2.0f : 1.0f;      // Hermitian quadrant weight
            atomicAdd(s3, base * wq * (red[0] + red[1] + red[2] + red[3]));
        }
    }
}

// sigma = 1024 * (s3/289)^(1/16);  out = K / sigma
__global__ void k_scale(const float* __restrict__ K, float* __restrict__ out,
                        const float* __restrict__ s3) {
    float sig = 1024.0f * exp2f(log2f((*s3) * (1.0f / 289.0f)) * 0.0625f);
    float inv = 1.0f / sig;
    int i = (blockIdx.x * 256 + threadIdx.x) * 4;   // 324 blocks exact
    f32x4 v = *(const f32x4*)(K + i);
    v *= inv;
    *(f32x4*)(out + i) = v;
}

extern "C" void kernel_launch(void* const* d_in, const int* in_sizes, int n_in,
                              void* d_out, int out_size, void* d_ws, size_t ws_size,
                              hipStream_t stream) {
    const float* K = (const float*)d_in[0];
    float* out = (float*)d_out;
    char* ws = (char*)d_ws;
    float* s3 = (float*)ws;
    bf16* bufX = (bf16*)(ws + 256);
    bf16* bufH = bufX + (size_t)NF * FSTRIDE;

    k_dftm<<<288, 256, 0, stream>>>(K, bufX, s3);                            // X
    k_gram<true,  false><<<NGRAM, 256, 0, stream>>>(bufX, bufH, nullptr);    // H1
    k_gram<true,  false><<<NGRAM, 256, 0, stream>>>(bufH, bufX, nullptr);    // H2
    k_gram<false, true ><<<NGRAM, 256, 0, stream>>>(bufX, nullptr, s3);      // ||H3||^2
    k_scale<<<NELEM / 1024, 256, 0, stream>>>(K, out, s3);
}

// Round 8
// 109.259 us; speedup vs baseline: 1.3727x; 1.0289x over previous
//
#include <hip/hip_runtime.h>
#include <hip/hip_bf16.h>

typedef __bf16 bf16;
typedef __attribute__((ext_vector_type(8))) __bf16 bf16x8;
typedef __attribute__((ext_vector_type(4))) float f32x4;
typedef __attribute__((ext_vector_type(4))) int i32x4;

#define CH 192
#define MAT (CH * CH)            // 36864
#define NF 145                   // canonical frequencies of 17x17 grid (conj symmetry)
#define FSTRIDE (2 * MAT)        // Re+Im per freq
#define NELEM (CH * CH * 9)      // 331776
#define XSCALE 9.765625e-4f      // 2^-10, exact; sigma = 1024*(s3/289)^(1/16)
#define W17 0.36959913571644626f // 2*pi/17
#define NGRAM (8 * 19 * 3)       // 456 gram blocks (435 active)

// ---------------------------------------------------------------------------
// sigma = ||G^3(K)||_F^(1/8) via 17x17 spectral sampling (exact Parseval).
// ROUND-5 CONFIGURATION (measured 109.4 us — best). Lessons pinned:
//  - r4: runtime trip counts spill v[] to scratch (+30 us). Staging FULLY
//    UNROLLED with compile-time indices.
//  - r6: spinner-block fusion of the scale (agent-scope polling) +40 us.
//    k_scale stays a separate dispatch.
//  - r7: MFMA-based DFT (k_dftm) regressed +3 us: its C-layout scatters X
//    stores across 16 freq planes (8-B chunks) vs k_dft's coalesced 128-B.
//    Keep the VALU k_dft with the LDS twiddle table.
//  - LDSR must be ==0 mod 8 (16-B aligned b128); 72 is the minimum
//    conflict-free stride -> 55296 B LDS, 2 blocks/CU. No occupancy lever.
// XCD pinning: freq f handled by blocks with blockIdx%8 == f%8.
// ws layout: [0] float s3; [256] bufX bf16 [f][2][a][o]; bufH (~21.4 MB ea).
// ---------------------------------------------------------------------------

// X[f][part][a][o] = DFT_17x17(K[o][a])(w_f) * 2^-10.  4 freqs/block, f%8 fixed.
// Twiddles from a 17-entry LDS table (built once; squares via index (2f)%17).
__global__ void k_dft(const float* __restrict__ K, bf16* __restrict__ X,
                      float* __restrict__ s3) {
    __shared__ float twc[17], tws[17];
    int bid = blockIdx.x;                 // 8 * 5 * 144 = 5760
    int xcd = bid & 7;
    int r = bid >> 3;
    int g4 = r / 144, sub = r % 144;
    int t = threadIdx.x;
    if (bid == 0 && t == 0) *s3 = 0.0f;   // stream-ordered: done before gram C
    if (t < 17) {
        float s, c;
        __sincosf(-W17 * (float)t, &s, &c);
        twc[t] = c; tws[t] = s;
    }
    int p = sub * 256 + t;                // p = a*192 + o
    int a = p / CH, o = p % CH;
    const float* src = K + (size_t)(o * CH + a) * 9;
    float kv[9];
#pragma unroll
    for (int i = 0; i < 9; ++i) kv[i] = src[i];
    __syncthreads();
#pragma unroll
    for (int jj = 0; jj < 4; ++jj) {
        int f = xcd + 8 * (g4 * 4 + jj);  // f % 8 == xcd
        if (f >= NF) break;               // uniform per block
        int fy, fx;
        if (f < 9) { fy = 0; fx = f; }
        else { int u = f - 9; fy = 1 + u / 17; fx = u % 17; }
        float pyr = twc[fy], pyi = tws[fy];
        float pxr = twc[fx], pxi = tws[fx];
        int fx2 = 2 * fx; if (fx2 >= 17) fx2 -= 17;
        int fy2 = 2 * fy; if (fy2 >= 17) fy2 -= 17;
        float px2r = twc[fx2], px2i = tws[fx2];
        float py2r = twc[fy2], py2i = tws[fy2];
        // row sums s_y = kv[y][0] + kv[y][1]*px + kv[y][2]*px^2  (kv real)
        float s0r = kv[0] + kv[1] * pxr + kv[2] * px2r, s0i = kv[1] * pxi + kv[2] * px2i;
        float s1r = kv[3] + kv[4] * pxr + kv[5] * px2r, s1i = kv[4] * pxi + kv[5] * px2i;
        float s2r = kv[6] + kv[7] * pxr + kv[8] * px2r, s2i = kv[7] * pxi + kv[8] * px2i;
        // total = s0 + py*s1 + py^2*s2
        float ar = s0r + pyr * s1r - pyi * s1i + py2r * s2r - py2i * s2i;
        float ai = s0i + pyr * s1i + pyi * s1r + py2r * s2i + py2i * s2r;
        size_t base = (size_t)f * FSTRIDE;
        X[base + p]       = (bf16)(ar * XSCALE);
        X[base + MAT + p] = (bf16)(ai * XSCALE);
    }
}

// One conj-gram round: OUT[m,n] = sum_k conj(X[m,k]) * X[n,k]  (per freq).
// Quadrants q=0:(0,0) q=1:(0,96) q=2:(96,96); WRITE emits (96,0)=conj-T(q=1).
// NORM weights q=1 by 2. Block 256 = 4 waves, wave = 48x48 complex.
#define LDSR 72                  // 64 + 8 bf16 pad (row stride 36 dwords)
#define SLAB (96 * LDSR)         // 6912 elems
#define OLDSR 104                // epilogue tile stride: 208 B = 13*16 (b128 rows)

template <bool WRITE, bool NORM>
__global__ __launch_bounds__(256, 2) void k_gram(const bf16* __restrict__ X,
                                                 bf16* __restrict__ Y,
                                                 float* __restrict__ s3) {
    __shared__ bf16 lds[4 * SLAB];      // Ar Ai Br Bi : 55296 B (epilogue reuses)
    __shared__ float red[4];
    int bid = blockIdx.x;
    int xcd = bid & 7, r = bid >> 3;
    int fi = r / 3, q = r % 3;          // q: 0=(0,0) 1=(0,96) 2=(96,96)
    int f = xcd + 8 * fi;
    if (f >= NF) return;                // uniform; before any barrier
    int row0 = (q == 2) ? 96 : 0;
    int col0 = (q >= 1) ? 96 : 0;
    bool diag = (q != 1);
    int sb2 = diag ? 0 : 2;             // B-slab base (diag reuses A slabs)
    const bf16* Xf = X + (size_t)f * FSTRIDE;

    int tid = threadIdx.x;
    int lane = tid & 63, w = tid >> 6;
    int wr = (w >> 1) * 48, wc = (w & 1) * 48;
    int ml = lane & 15, kq = (lane >> 4) * 8;

    f32x4 cr[3][3], ci[3][3];
#pragma unroll
    for (int i = 0; i < 3; ++i)
#pragma unroll
        for (int j = 0; j < 3; ++j) {
            cr[i][j] = f32x4{0.f, 0.f, 0.f, 0.f};
            ci[i][j] = f32x4{0.f, 0.f, 0.f, 0.f};
        }

    for (int kc = 0; kc < CH; kc += 64) {
        // FULLY UNROLLED staging (compile-time v[] indices — no scratch!)
        i32x4 v[12];
#pragma unroll
        for (int s = 0; s < 2; ++s) {               // A slabs (always)
            const bf16* src = Xf + (s ? MAT : 0) + (size_t)row0 * CH + kc;
#pragma unroll
            for (int j = 0; j < 3; ++j) {
                int chunk = j * 256 + tid;
                int rr = chunk >> 3, c8 = chunk & 7;
                v[s * 3 + j] = *(const i32x4*)(src + rr * CH + c8 * 8);
            }
        }
        if (!diag) {
#pragma unroll
            for (int s = 2; s < 4; ++s) {           // B slabs (off-diag only)
                const bf16* src = Xf + ((s & 1) ? MAT : 0) + (size_t)col0 * CH + kc;
#pragma unroll
                for (int j = 0; j < 3; ++j) {
                    int chunk = j * 256 + tid;
                    int rr = chunk >> 3, c8 = chunk & 7;
                    v[s * 3 + j] = *(const i32x4*)(src + rr * CH + c8 * 8);
                }
            }
        }
        __syncthreads();
#pragma unroll
        for (int s = 0; s < 2; ++s)
#pragma unroll
            for (int j = 0; j < 3; ++j) {
                int chunk = j * 256 + tid;
                int rr = chunk >> 3, c8 = chunk & 7;
                *(i32x4*)&lds[s * SLAB + rr * LDSR + c8 * 8] = v[s * 3 + j];
            }
        if (!diag) {
#pragma unroll
            for (int s = 2; s < 4; ++s)
#pragma unroll
                for (int j = 0; j < 3; ++j) {
                    int chunk = j * 256 + tid;
                    int rr = chunk >> 3, c8 = chunk & 7;
                    *(i32x4*)&lds[s * SLAB + rr * LDSR + c8 * 8] = v[s * 3 + j];
                }
        }
        __syncthreads();

#pragma unroll
        for (int ks = 0; ks < 64; ks += 32) {
            bf16x8 ar[3], ai[3], nai[3], br[3], bi[3];
            int ko = ks + kq;
#pragma unroll
            for (int mt = 0; mt < 3; ++mt) {
                ar[mt] = *(const bf16x8*)&lds[0 * SLAB + (wr + mt * 16 + ml) * LDSR + ko];
                ai[mt] = *(const bf16x8*)&lds[1 * SLAB + (wr + mt * 16 + ml) * LDSR + ko];
                br[mt] = *(const bf16x8*)&lds[(sb2 + 0) * SLAB + (wc + mt * 16 + ml) * LDSR + ko];
                bi[mt] = *(const bf16x8*)&lds[(sb2 + 1) * SLAB + (wc + mt * 16 + ml) * LDSR + ko];
                i32x4 u = __builtin_bit_cast(i32x4, ai[mt]);
                u ^= 0x80008000;   // negate 8 bf16
                nai[mt] = __builtin_bit_cast(bf16x8, u);
            }
#pragma unroll
            for (int mt = 0; mt < 3; ++mt)
#pragma unroll
                for (int nt = 0; nt < 3; ++nt) {
                    cr[mt][nt] = __builtin_amdgcn_mfma_f32_16x16x32_bf16(ar[mt],  br[nt], cr[mt][nt], 0, 0, 0);
                    cr[mt][nt] = __builtin_amdgcn_mfma_f32_16x16x32_bf16(ai[mt],  bi[nt], cr[mt][nt], 0, 0, 0);
                    ci[mt][nt] = __builtin_amdgcn_mfma_f32_16x16x32_bf16(ar[mt],  bi[nt], ci[mt][nt], 0, 0, 0);
                    ci[mt][nt] = __builtin_amdgcn_mfma_f32_16x16x32_bf16(nai[mt], br[nt], ci[mt][nt], 0, 0, 0);
                }
        }
    }

    if (WRITE) {
        // frag -> LDS tile(s) -> coalesced b128 row stores; q=1 scatters conj
        // into a pre-transposed second tile for the (96,0) quadrant.
        bf16* tileA = lds;
        bf16* tileB = lds + 96 * OLDSR;     // 19968 B each, 39936 <= 55296
        bf16* Yf = Y + (size_t)f * FSTRIDE;
        int lr0 = wr + (lane >> 4) * 4;
        int lc0 = wc + ml;
#pragma unroll
        for (int part = 0; part < 2; ++part) {
            __syncthreads();   // frag LDS reads / prev part's global reads done
#pragma unroll
            for (int mt = 0; mt < 3; ++mt)
#pragma unroll
                for (int nt = 0; nt < 3; ++nt)
#pragma unroll
                    for (int rr = 0; rr < 4; ++rr) {
                        float vv = part ? ci[mt][nt][rr] : cr[mt][nt][rr];
                        int rrow = lr0 + mt * 16 + rr;
                        int ccol = lc0 + nt * 16;
                        tileA[rrow * OLDSR + ccol] = (bf16)vv;
                        if (q == 1)
                            tileB[ccol * OLDSR + rrow] = (bf16)(part ? -vv : vv);
                    }
            __syncthreads();
            bf16* dst = Yf + (part ? MAT : 0) + (size_t)row0 * CH + col0;
            for (int ch = tid; ch < 96 * 12; ch += 256) {
                int rw = ch / 12, cc = ch % 12;
                *(i32x4*)&dst[(size_t)rw * CH + cc * 8] = *(const i32x4*)&tileA[rw * OLDSR + cc * 8];
            }
            if (q == 1) {
                bf16* dst2 = Yf + (part ? MAT : 0) + (size_t)col0 * CH + row0;
                for (int ch = tid; ch < 96 * 12; ch += 256) {
                    int rw = ch / 12, cc = ch % 12;
                    *(i32x4*)&dst2[(size_t)rw * CH + cc * 8] = *(const i32x4*)&tileB[rw * OLDSR + cc * 8];
                }
            }
        }
    }
    if (NORM) {
        float loc = 0.f;
#pragma unroll
        for (int mt = 0; mt < 3; ++mt)
#pragma unroll
            for (int nt = 0; nt < 3; ++nt)
#pragma unroll
                for (int rr = 0; rr < 4; ++rr)
                    loc += cr[mt][nt][rr] * cr[mt][nt][rr] + ci[mt][nt][rr] * ci[mt][nt][rr];
#pragma unroll
        for (int off = 32; off > 0; off >>= 1) loc += __shfl_down(loc, off, 64);
        if (lane == 0) red[w] = loc;
        __syncthreads();
        if (tid == 0) {
            float base = (f == 0) ? 1.0f : 2.0f;    // conj-pair weight over freqs
            float wq = (q == 1) ? 2.0f : 1.0f;      // Hermitian quadrant weight
            atomicAdd(s3, base * wq * (red[0] + red[1] + red[2] + red[3]));
        }
    }
}

// sigma = 1024 * (s3/289)^(1/16);  out = K / sigma
__global__ void k_scale(const float* __restrict__ K, float* __restrict__ out,
                        const float* __restrict__ s3) {
    float sig = 1024.0f * exp2f(log2f((*s3) * (1.0f / 289.0f)) * 0.0625f);
    float inv = 1.0f / sig;
    int i = (blockIdx.x * 256 + threadIdx.x) * 4;   // 324 blocks exact
    f32x4 v = *(const f32x4*)(K + i);
    v *= inv;
    *(f32x4*)(out + i) = v;
}

extern "C" void kernel_launch(void* const* d_in, const int* in_sizes, int n_in,
                              void* d_out, int out_size, void* d_ws, size_t ws_size,
                              hipStream_t stream) {
    const float* K = (const float*)d_in[0];
    float* out = (float*)d_out;
    char* ws = (char*)d_ws;
    float* s3 = (float*)ws;
    bf16* bufX = (bf16*)(ws + 256);
    bf16* bufH = bufX + (size_t)NF * FSTRIDE;

    k_dft<<<8 * 5 * 144, 256, 0, stream>>>(K, bufX, s3);                     // X
    k_gram<true,  false><<<NGRAM, 256, 0, stream>>>(bufX, bufH, nullptr);    // H1
    k_gram<true,  false><<<NGRAM, 256, 0, stream>>>(bufH, bufX, nullptr);    // H2
    k_gram<false, true ><<<NGRAM, 256, 0, stream>>>(bufX, nullptr, s3);      // ||H3||^2
    k_scale<<<NELEM / 1024, 256, 0, stream>>>(K, out, s3);
}